// Round 5
// baseline (1207.463 us; speedup 1.0000x reference)
//
#include <hip/hip_runtime.h>

// CapsuleLayer — B=32, I=2048, N=32, D=32, ROUTINGS=3.
// Dtype-adaptive (runtime sniff of W: bf16 vs fp32), fully vanilla HIP:
// no MFMA / asm / bf16 headers. One block per (i, 4-batch group); phase 1
// computes u_hat rows with fp32 VALU dots into LDS (fp32, padded stride 33);
// phase 2 runs the 3-iter routing in registers with width-32 shuffles.

#define IC 2048
#define NS 33              // floats per n-row in LDS (pad +1 -> conflict-free cols)
#define BS (32 * NS)       // 1056 floats per batch row

__device__ __forceinline__ float bfbits_to_f(unsigned short h) {
    return __uint_as_float(((unsigned)h) << 16);
}
__device__ __forceinline__ float f_lo(unsigned u) { return __uint_as_float(u << 16); }
__device__ __forceinline__ float f_hi(unsigned u) { return __uint_as_float(u & 0xFFFF0000u); }
__device__ __forceinline__ unsigned short f_to_bfbits(float f) {  // RNE
    unsigned u = __float_as_uint(f);
    u += 0x7FFFu + ((u >> 16) & 1u);
    return (unsigned short)(u >> 16);
}

template<bool FP32>
__device__ __forceinline__ void caps_body(
    const void* __restrict__ xp, const void* __restrict__ Wp,
    void* __restrict__ outp, float (*uh)[BS], float (*xl)[32],
    unsigned i, unsigned g, unsigned tid)
{
    // ---- stage x[g*4 .. g*4+3, i, :] into LDS ----
    if (tid < 128) {
        const unsigned b = tid >> 5, k = tid & 31;
        const size_t idx = ((size_t)(g * 4 + b) * IC + i) * 32 + k;
        xl[b][k] = FP32 ? ((const float*)xp)[idx]
                        : bfbits_to_f(((const unsigned short*)xp)[idx]);
    }
    __syncthreads();

    // ---- phase 1: u_hat[b, c] = sum_k x[b,k] * W[i, c, k], c = n*32+d ----
    {
        const unsigned b = tid >> 6, cg = tid & 63;
        float xr[32];
        #pragma unroll
        for (int k = 0; k < 32; ++k) xr[k] = xl[b][k];

        for (unsigned cc = 0; cc < 16; ++cc) {
            const unsigned c = cc * 64 + cg;    // 64 consecutive rows per wave-pair
            float acc = 0.f;
            if (FP32) {
                const float4* wr = (const float4*)(
                    (const float*)Wp + (size_t)i * 32768 + (size_t)c * 32);
                #pragma unroll
                for (int j = 0; j < 8; ++j) {
                    const float4 v = wr[j];
                    acc += v.x * xr[4*j+0] + v.y * xr[4*j+1]
                         + v.z * xr[4*j+2] + v.w * xr[4*j+3];
                }
            } else {
                const uint4* wr = (const uint4*)(
                    (const unsigned short*)Wp + (size_t)i * 32768 + (size_t)c * 32);
                #pragma unroll
                for (int j = 0; j < 4; ++j) {
                    const uint4 v = wr[j];
                    acc += f_lo(v.x) * xr[8*j+0] + f_hi(v.x) * xr[8*j+1]
                         + f_lo(v.y) * xr[8*j+2] + f_hi(v.y) * xr[8*j+3]
                         + f_lo(v.z) * xr[8*j+4] + f_hi(v.z) * xr[8*j+5]
                         + f_lo(v.w) * xr[8*j+6] + f_hi(v.w) * xr[8*j+7];
                }
            }
            uh[b][(c >> 5) * NS + (c & 31)] = acc;
        }
    }
    __syncthreads();

    // ---- phase 2: 3-iteration dynamic routing; thread = (bb, s) ----
    if (tid < 128) {
        const unsigned bb = tid >> 5, s = tid & 31;
        const float* ub = uh[bb];

        float row[32];   // U[bb, n=s, d]
        float col[32];   // U[bb, n, d=s]
        #pragma unroll
        for (int d = 0; d < 32; ++d) row[d] = ub[s * NS + d];
        #pragma unroll
        for (int n = 0; n < 32; ++n) col[n] = ub[n * NS + s];

        float r = 0.f, o = 0.f;

        // r=0: softmax(0) = uniform 1/32
        {
            float acc = 0.f;
            #pragma unroll
            for (int n = 0; n < 32; ++n) acc += col[n];
            o = fmaxf(acc * (1.0f / 32.0f), 0.f);
            float rr = 0.f;
            #pragma unroll
            for (int d = 0; d < 32; ++d) rr += __shfl(o, d, 32) * row[d];
            r = rr;
        }

        for (int iter = 1; iter < 3; ++iter) {
            float mx = r;
            #pragma unroll
            for (int off = 16; off >= 1; off >>= 1)
                mx = fmaxf(mx, __shfl_xor(mx, off, 32));
            const float e = __expf(r - mx);
            float sm = e;
            #pragma unroll
            for (int off = 16; off >= 1; off >>= 1)
                sm += __shfl_xor(sm, off, 32);
            const float c = e / sm;

            float acc = 0.f;
            #pragma unroll
            for (int n = 0; n < 32; ++n) acc += __shfl(c, n, 32) * col[n];
            o = fmaxf(acc, 0.f);

            if (iter < 2) {
                float rr = 0.f;
                #pragma unroll
                for (int d = 0; d < 32; ++d) rr += __shfl(o, d, 32) * row[d];
                r += rr;
            }
        }

        const size_t oidx = ((size_t)(g * 4 + bb) * IC + i) * 32 + s;
        if (FP32) ((float*)outp)[oidx] = o;
        else      ((unsigned short*)outp)[oidx] = f_to_bfbits(o);
    }
}

__global__ void CapsuleLayer_72224170049868_kernel(
    const void* __restrict__ x, const void* __restrict__ W,
    void* __restrict__ out)
{
    __shared__ float uh[4][BS];      // 16.9 KB
    __shared__ float xl[4][32];
    __shared__ int   flagS;

    const unsigned bid = blockIdx.x;
    const unsigned i = ((bid >> 6) << 3) | (bid & 7);   // 0..2047
    const unsigned g = (bid >> 3) & 7;                  // 4-batch group, 0..7
    const unsigned tid = threadIdx.x;

    // dtype sniff: W ~ U(+-0.433). True-bf16 buffer: every even halfword has
    // exponent <= 125. fp32 buffer: even halfwords are random mantissa bits ->
    // exponent >= 126 appears within 32 samples with P ~ 1 - 6e-11.
    if (tid == 0) {
        int f = 0;
        const unsigned* Wu = (const unsigned*)W;
        for (int j = 0; j < 32; ++j)
            if (((Wu[j] >> 7) & 0xFFu) >= 126u) f = 1;
        flagS = f;
    }
    __syncthreads();
    const bool is_fp32 = (flagS != 0);

    if (is_fp32) caps_body<true >(x, W, out, uh, xl, i, g, tid);
    else         caps_body<false>(x, W, out, uh, xl, i, g, tid);
}

extern "C" void kernel_launch(void* const* d_in, const int* in_sizes, int n_in,
                              void* d_out, int out_size, void* d_ws, size_t ws_size,
                              hipStream_t stream) {
    (void)d_ws; (void)ws_size; (void)out_size;
    // defensive input-order detection: x = 2,097,152 elems, W = 67,108,864
    const int swap = (n_in >= 2 && in_sizes[0] > in_sizes[1]) ? 1 : 0;
    const void* x = d_in[swap ? 1 : 0];
    const void* W = d_in[swap ? 0 : 1];

    CapsuleLayer_72224170049868_kernel<<<dim3(16384), dim3(256), 0, stream>>>(x, W, d_out);
}